// Round 1
// baseline (192.376 us; speedup 1.0000x reference)
//
#include <hip/hip_runtime.h>
#include <hip/hip_bf16.h>

typedef unsigned short u16;
typedef __bf16 bf16x8 __attribute__((ext_vector_type(8)));
typedef float f32x4 __attribute__((ext_vector_type(4)));
typedef unsigned short u16x8 __attribute__((ext_vector_type(8)));

__device__ __forceinline__ float bf2f(u16 u) {
  unsigned int x = ((unsigned int)u) << 16;
  return __builtin_bit_cast(float, x);
}
__device__ __forceinline__ u16 f2bf(float f) {
  unsigned int x = __builtin_bit_cast(unsigned int, f);
  x = x + 0x7FFFu + ((x >> 16) & 1u);
  return (u16)(x >> 16);
}

// ---------------- cast X fp32 -> bf16 ----------------
__global__ __launch_bounds__(256) void cast_x_kernel(const float* __restrict__ X,
                                                     u16* __restrict__ Xb, long n) {
  long i = ((long)blockIdx.x * 256 + threadIdx.x) * 8;
  if (i >= n) return;
  float4 a = *reinterpret_cast<const float4*>(X + i);
  float4 b = *reinterpret_cast<const float4*>(X + i + 4);
  u16x8 o;
  o[0] = f2bf(a.x); o[1] = f2bf(a.y); o[2] = f2bf(a.z); o[3] = f2bf(a.w);
  o[4] = f2bf(b.x); o[5] = f2bf(b.y); o[6] = f2bf(b.z); o[7] = f2bf(b.w);
  *reinterpret_cast<u16x8*>(Xb + i) = o;
}

// ------- transpose+cast W (fp32 [1024][1024] -> bf16 [n][k], optional scale) -------
__global__ __launch_bounds__(256) void transpose_cast_w(const float* __restrict__ W,
                                                        u16* __restrict__ Wt, float scale) {
  __shared__ u16 t[64][72];
  const int r0 = blockIdx.y * 64;  // k dim
  const int c0 = blockIdx.x * 64;  // n dim
  const int tid = threadIdx.x;
#pragma unroll
  for (int i = 0; i < 4; ++i) {
    int slot = tid + 256 * i;   // 0..1023, float4 granules
    int lr = slot >> 4;
    int lc4 = slot & 15;
    float4 v = *reinterpret_cast<const float4*>(W + (long)(r0 + lr) * 1024 + c0 + lc4 * 4);
    t[lr][lc4 * 4 + 0] = f2bf(v.x * scale);
    t[lr][lc4 * 4 + 1] = f2bf(v.y * scale);
    t[lr][lc4 * 4 + 2] = f2bf(v.z * scale);
    t[lr][lc4 * 4 + 3] = f2bf(v.w * scale);
  }
  __syncthreads();
#pragma unroll
  for (int i = 0; i < 2; ++i) {
    int slot = tid + 256 * i;   // 0..511, short8 granules
    int orow = slot >> 3;
    int oc = slot & 7;
    u16x8 o;
#pragma unroll
    for (int j = 0; j < 8; ++j) o[j] = t[oc * 8 + j][orow];
    *reinterpret_cast<u16x8*>(Wt + (long)(c0 + orow) * 1024 + r0 + oc * 8) = o;
  }
}

// ------- transpose V bf16 per batch: in [2048][1024] -> out [1024][2048] -------
__global__ __launch_bounds__(256) void transpose_v(const u16* __restrict__ V,
                                                   u16* __restrict__ Vt) {
  __shared__ u16 t[64][72];
  const int z = blockIdx.z;
  const u16* in = V + (long)z * 2048 * 1024;
  u16* out = Vt + (long)z * 1024 * 2048;
  const int r0 = blockIdx.y * 64;  // t dim
  const int c0 = blockIdx.x * 64;  // e dim
  const int tid = threadIdx.x;
#pragma unroll
  for (int i = 0; i < 2; ++i) {
    int slot = tid + 256 * i;
    int lr = slot >> 3, lc = slot & 7;
    u16x8 v = *reinterpret_cast<const u16x8*>(in + (long)(r0 + lr) * 1024 + c0 + lc * 8);
#pragma unroll
    for (int j = 0; j < 8; ++j) t[lr][lc * 8 + j] = v[j];
  }
  __syncthreads();
#pragma unroll
  for (int i = 0; i < 2; ++i) {
    int slot = tid + 256 * i;
    int orow = slot >> 3, oc = slot & 7;
    u16x8 o;
#pragma unroll
    for (int j = 0; j < 8; ++j) o[j] = t[oc * 8 + j][orow];
    *reinterpret_cast<u16x8*>(out + (long)(c0 + orow) * 2048 + r0 + oc * 8) = o;
  }
}

// ---------------- NT GEMM: C[M][N] = sum_k A[m][k] * B[n][k] ----------------
// A: [M][K] bf16 row-major, B: [N][K] bf16 row-major.
// 128x128 tile, 4 waves (2x2), each wave 64x64 (4x4 fragments of 16x16x32 MFMA), BK=64.
// OB: 1 -> bf16 output, 0 -> fp32 output.
// SU: skip upper-triangle blocks (bn > bm)   [S = Q K^T, causal]
// KL: limit k-loop to m0+128                 [O = P V, causal]
template <int OB, int SU, int KL>
__global__ __launch_bounds__(256, 2) void gemm_nt(const u16* __restrict__ Ag,
                                                  const u16* __restrict__ Bg,
                                                  void* __restrict__ Cg,
                                                  int M, int N, int K,
                                                  long sA, long sB, long sC) {
  const int bn = blockIdx.x, bm = blockIdx.y, bz = blockIdx.z;
  if (SU && bn > bm) return;
  const u16* A = Ag + (long)bz * sA;
  const u16* B = Bg + (long)bz * sB;
  const int m0 = bm * 128, n0 = bn * 128;
  int kEnd = K;
  if (KL) kEnd = (m0 + 128 < K) ? (m0 + 128) : K;

  __shared__ u16 ldsA[128 * 64];
  __shared__ u16 ldsB[128 * 64];

  const int tid = threadIdx.x;
  const int lane = tid & 63;
  const int wid = tid >> 6;
  const int wm = wid >> 1, wn = wid & 1;
  const int l16 = lane & 15, lh = lane >> 4;

  f32x4 acc[4][4];
#pragma unroll
  for (int mi = 0; mi < 4; ++mi)
#pragma unroll
    for (int ni = 0; ni < 4; ++ni) acc[mi][ni] = (f32x4)(0.0f);

  for (int k0 = 0; k0 < kEnd; k0 += 64) {
    u16x8 ra[4], rb[4];
#pragma unroll
    for (int i = 0; i < 4; ++i) {
      int slot = tid + 256 * i;           // 0..1023
      int row = slot >> 3, sl = slot & 7; // row, 16B-slot in K
      ra[i] = *reinterpret_cast<const u16x8*>(A + (long)(m0 + row) * K + k0 + sl * 8);
      rb[i] = *reinterpret_cast<const u16x8*>(B + (long)(n0 + row) * K + k0 + sl * 8);
    }
    __syncthreads();  // previous iteration's ds_reads done
#pragma unroll
    for (int i = 0; i < 4; ++i) {
      int slot = tid + 256 * i;
      int row = slot >> 3, sl = slot & 7;
      int sp = sl ^ (row & 7);            // XOR swizzle: kills 128B-stride bank conflict
      *reinterpret_cast<u16x8*>(&ldsA[row * 64 + sp * 8]) = ra[i];
      *reinterpret_cast<u16x8*>(&ldsB[row * 64 + sp * 8]) = rb[i];
    }
    __syncthreads();
#pragma unroll
    for (int kk = 0; kk < 2; ++kk) {
      bf16x8 af[4], bfr[4];
#pragma unroll
      for (int mi = 0; mi < 4; ++mi) {
        int row = wm * 64 + mi * 16 + l16;
        int sp = (kk * 4 + lh) ^ (row & 7);
        af[mi] = *reinterpret_cast<const bf16x8*>(&ldsA[row * 64 + sp * 8]);
      }
#pragma unroll
      for (int ni = 0; ni < 4; ++ni) {
        int row = wn * 64 + ni * 16 + l16;
        int sp = (kk * 4 + lh) ^ (row & 7);
        bfr[ni] = *reinterpret_cast<const bf16x8*>(&ldsB[row * 64 + sp * 8]);
      }
#pragma unroll
      for (int mi = 0; mi < 4; ++mi)
#pragma unroll
        for (int ni = 0; ni < 4; ++ni)
          acc[mi][ni] = __builtin_amdgcn_mfma_f32_16x16x32_bf16(af[mi], bfr[ni], acc[mi][ni], 0, 0, 0);
    }
  }

  // epilogue: D row = (lane>>4)*4 + r, col = lane&15 (m89-verified layout)
  const int rbase = m0 + wm * 64 + lh * 4;
  const int cbase = n0 + wn * 64 + l16;
  if constexpr (OB) {
    u16* C = (u16*)Cg + (long)bz * sC;
#pragma unroll
    for (int mi = 0; mi < 4; ++mi)
#pragma unroll
      for (int ni = 0; ni < 4; ++ni)
#pragma unroll
        for (int r = 0; r < 4; ++r)
          C[(long)(rbase + mi * 16 + r) * N + (cbase + ni * 16)] = f2bf(acc[mi][ni][r]);
  } else {
    float* C = (float*)Cg + (long)bz * sC;
#pragma unroll
    for (int mi = 0; mi < 4; ++mi)
#pragma unroll
      for (int ni = 0; ni < 4; ++ni)
#pragma unroll
        for (int r = 0; r < 4; ++r)
          C[(long)(rbase + mi * 16 + r) * N + (cbase + ni * 16)] = acc[mi][ni][r];
  }
}

// ---------------- causal row softmax, in-place on bf16 S ----------------
// grid = B*T blocks; row q keeps k<=q, writes zeros for k>q.
__global__ __launch_bounds__(256) void softmax_kernel(u16* __restrict__ S, int T) {
  __shared__ float red[8];
  const long base = (long)blockIdx.x * T;
  const int q = blockIdx.x & (T - 1);
  const int len = q + 1;
  const int tid = threadIdx.x, lane = tid & 63, wid = tid >> 6;
  u16* row = S + base;

  float m = -1e30f;
  for (int k = tid; k < len; k += 256) m = fmaxf(m, bf2f(row[k]));
#pragma unroll
  for (int o = 32; o > 0; o >>= 1) m = fmaxf(m, __shfl_down(m, o));
  if (lane == 0) red[wid] = m;
  __syncthreads();
  const float mx = fmaxf(fmaxf(red[0], red[1]), fmaxf(red[2], red[3]));

  float s = 0.0f;
  for (int k = tid; k < len; k += 256) s += __expf(bf2f(row[k]) - mx);
#pragma unroll
  for (int o = 32; o > 0; o >>= 1) s += __shfl_down(s, o);
  if (lane == 0) red[4 + wid] = s;
  __syncthreads();
  const float inv = 1.0f / (red[4] + red[5] + red[6] + red[7]);

  for (int k = tid; k < T; k += 256) {
    float p = (k < len) ? __expf(bf2f(row[k]) - mx) * inv : 0.0f;
    row[k] = f2bf(p);
  }
}

extern "C" void kernel_launch(void* const* d_in, const int* in_sizes, int n_in,
                              void* d_out, int out_size, void* d_ws, size_t ws_size,
                              hipStream_t stream) {
  const float* X  = (const float*)d_in[0];
  const float* Wq = (const float*)d_in[1];
  const float* Wk = (const float*)d_in[2];
  const float* Wv = (const float*)d_in[3];

  // workspace layout (u16 elements)
  u16* Xb = (u16*)d_ws;                 // 8192*1024
  u16* Wt = Xb + 8388608;               // 3 * 1024*1024 (transposed, Wq pre-scaled by 1/32)
  u16* Qb = Wt + 3145728;               // 8192*1024
  u16* Kb = Qb + 8388608;
  u16* Vb = Kb + 8388608;
  u16* Vt = Vb + 8388608;               // [b][1024][2048]
  u16* S  = Vt + 8388608;               // [b][2048][2048] scores->probs
  // total = 123.7 MB

  cast_x_kernel<<<4096, 256, 0, stream>>>(X, Xb, 8388608L);
  transpose_cast_w<<<dim3(16, 16), 256, 0, stream>>>(Wq, Wt,           1.0f / 32.0f);
  transpose_cast_w<<<dim3(16, 16), 256, 0, stream>>>(Wk, Wt + 1048576, 1.0f);
  transpose_cast_w<<<dim3(16, 16), 256, 0, stream>>>(Wv, Wt + 2097152, 1.0f);

  // QKV projection: [8192,1024] x [1024,1024]^T-stored, z = {Q,K,V}
  gemm_nt<1, 0, 0><<<dim3(8, 64, 3), 256, 0, stream>>>(
      Xb, Wt, Qb, 8192, 1024, 1024, 0L, 1048576L, 8388608L);

  // S = Q K^T per batch (Q pre-scaled), skip fully-masked upper blocks
  gemm_nt<1, 1, 0><<<dim3(16, 16, 4), 256, 0, stream>>>(
      Qb, Kb, S, 2048, 2048, 1024, 2097152L, 2097152L, 4194304L);

  softmax_kernel<<<8192, 256, 0, stream>>>(S, 2048);

  transpose_v<<<dim3(16, 32, 4), 256, 0, stream>>>(Vb, Vt);

  // O = P V per batch, k-loop limited to m0+128 (causal)
  gemm_nt<0, 0, 1><<<dim3(8, 16, 4), 256, 0, stream>>>(
      S, Vt, (float*)d_out, 2048, 1024, 2048, 4194304L, 2097152L, 2097152L);
}

// Round 2
// 178.890 us; speedup vs baseline: 1.0754x; 1.0754x over previous
//
#include <hip/hip_runtime.h>
#include <hip/hip_bf16.h>

typedef unsigned short u16;
typedef __bf16 bf16x8 __attribute__((ext_vector_type(8)));
typedef float f32x4 __attribute__((ext_vector_type(4)));
typedef unsigned short u16x8 __attribute__((ext_vector_type(8)));
typedef unsigned short u16x4 __attribute__((ext_vector_type(4)));

__device__ __forceinline__ float bf2f(u16 u) {
  unsigned int x = ((unsigned int)u) << 16;
  return __builtin_bit_cast(float, x);
}
__device__ __forceinline__ u16 f2bf(float f) {
  unsigned int x = __builtin_bit_cast(unsigned int, f);
  x = x + 0x7FFFu + ((x >> 16) & 1u);
  return (u16)(x >> 16);
}

// async global->LDS, 16B per lane; LDS dest is wave-uniform base + lane*16.
// AS1 ptr from integer (generic global == AS1 value); AS3 ptr via low-32-bit
// truncation of the generic LDS address (shared aperture is 4GB-aligned).
__device__ __forceinline__ void gload_lds16(const u16* g, u16* l) {
  __builtin_amdgcn_global_load_lds(
      (const __attribute__((address_space(1))) unsigned int*)(unsigned long long)(uintptr_t)g,
      (__attribute__((address_space(3))) unsigned int*)(unsigned int)(uintptr_t)l,
      16, 0, 0);
}

// ---------------- cast X fp32 -> bf16 ----------------
__global__ __launch_bounds__(256) void cast_x_kernel(const float* __restrict__ X,
                                                     u16* __restrict__ Xb, long n) {
  long i = ((long)blockIdx.x * 256 + threadIdx.x) * 8;
  if (i >= n) return;
  float4 a = *reinterpret_cast<const float4*>(X + i);
  float4 b = *reinterpret_cast<const float4*>(X + i + 4);
  u16x8 o;
  o[0] = f2bf(a.x); o[1] = f2bf(a.y); o[2] = f2bf(a.z); o[3] = f2bf(a.w);
  o[4] = f2bf(b.x); o[5] = f2bf(b.y); o[6] = f2bf(b.z); o[7] = f2bf(b.w);
  *reinterpret_cast<u16x8*>(Xb + i) = o;
}

// ------- transpose+cast W (fp32 [1024][1024] -> bf16 [n][k], optional scale) -------
__global__ __launch_bounds__(256) void transpose_cast_w(const float* __restrict__ W,
                                                        u16* __restrict__ Wt, float scale) {
  __shared__ u16 t[64][72];
  const int r0 = blockIdx.y * 64;  // k dim
  const int c0 = blockIdx.x * 64;  // n dim
  const int tid = threadIdx.x;
#pragma unroll
  for (int i = 0; i < 4; ++i) {
    int slot = tid + 256 * i;
    int lr = slot >> 4;
    int lc4 = slot & 15;
    float4 v = *reinterpret_cast<const float4*>(W + (long)(r0 + lr) * 1024 + c0 + lc4 * 4);
    t[lr][lc4 * 4 + 0] = f2bf(v.x * scale);
    t[lr][lc4 * 4 + 1] = f2bf(v.y * scale);
    t[lr][lc4 * 4 + 2] = f2bf(v.z * scale);
    t[lr][lc4 * 4 + 3] = f2bf(v.w * scale);
  }
  __syncthreads();
#pragma unroll
  for (int i = 0; i < 2; ++i) {
    int slot = tid + 256 * i;
    int orow = slot >> 3;
    int oc = slot & 7;
    u16x8 o;
#pragma unroll
    for (int j = 0; j < 8; ++j) o[j] = t[oc * 8 + j][orow];
    *reinterpret_cast<u16x8*>(Wt + (long)(c0 + orow) * 1024 + r0 + oc * 8) = o;
  }
}

// ---------------- NT GEMM core: C[M][N] = sum_k A[m][k] * B[n][k] ----------------
// 128x128 tile, 4 waves (2x2 of 64x64), BK=64, global_load_lds width-16 staging,
// linear LDS [128][64] (m97 structure).
// MODE 0: fused QKV. grid 1536 (1D, 2D-chunk XCD swizzle). A=Xb[8192][1024],
//         B=Wt[3072][1024]. Q,K written bf16 [8192][1024]; V written TRANSPOSED
//         to Vt[b][1024][2048].
// MODE 1: S = Q K^T per batch. grid (16,16,4), skip bn>bm, bf16 out [2048][2048].
// MODE 2: O = P V per batch. grid (8,16,4), kEnd=m0+128, f32 out [2048][1024].
template <int MODE>
__global__ __launch_bounds__(256, 2) void gemm_nt(const u16* __restrict__ Ag,
                                                  const u16* __restrict__ Bg,
                                                  void* __restrict__ Cg,
                                                  int K, long sA, long sB, long sC) {
  int bm, bn, bz;
  if constexpr (MODE == 0) {
    const int id = blockIdx.x;          // 0..1535
    const int xcd = id & 7, j = id >> 3; // j: 0..191
    const int cx = xcd & 1, cy = xcd >> 1;
    bn = cx * 12 + j % 12;               // 0..23
    bm = cy * 16 + j / 12;               // 0..63
    bz = 0;
  } else if constexpr (MODE == 1) {
    const int id = blockIdx.y * 16 + blockIdx.x;  // 0..255 (per z; 256%8==0)
    const int xcd = id & 7, j = id >> 3;          // j: 0..31
    bn = j & 15;
    bm = (j >> 4) ? (15 - xcd) : xcd;    // rows (x,15-x): balanced triangle
    bz = blockIdx.z;
    if (bn > bm) return;
  } else {
    const int id = blockIdx.y * 8 + blockIdx.x;   // 0..127 (per z; 128%8==0)
    const int xcd = id & 7, j = id >> 3;          // j: 0..15
    bn = j & 7;
    bm = (j >> 3) ? (15 - xcd) : xcd;    // balanced: work ∝ bm+1
    bz = blockIdx.z;
  }

  const u16* A = Ag + (long)bz * sA;
  const u16* B = Bg + (long)bz * sB;
  const int m0 = bm * 128, n0 = bn * 128;
  int kEnd = K;
  if constexpr (MODE == 2) kEnd = m0 + 128;  // causal k-limit

  __shared__ u16 ldsA[8192];
  __shared__ u16 ldsB[8192];

  const int tid = threadIdx.x;
  const int lane = tid & 63;
  const int wid = tid >> 6;
  const int wm = wid >> 1, wn = wid & 1;
  const int l16 = lane & 15, lh = lane >> 4;
  const int srow = lane >> 3, scol = (lane & 7) * 8;

  f32x4 acc[4][4];
#pragma unroll
  for (int mi = 0; mi < 4; ++mi)
#pragma unroll
    for (int ni = 0; ni < 4; ++ni) acc[mi][ni] = (f32x4)(0.0f);

  for (int k0 = 0; k0 < kEnd; k0 += 64) {
    __syncthreads();  // all waves done reading LDS of previous tile
#pragma unroll
    for (int s = 0; s < 4; ++s) {
      const int seg = wid * 4 + s;           // 0..15 (1KB segments)
      const int row = seg * 8 + srow;        // 0..127
      gload_lds16(A + (long)(m0 + row) * K + k0 + scol, &ldsA[seg * 512]);
      gload_lds16(B + (long)(n0 + row) * K + k0 + scol, &ldsB[seg * 512]);
    }
    __syncthreads();  // drains vmcnt -> LDS tile ready
#pragma unroll
    for (int kk = 0; kk < 2; ++kk) {
      bf16x8 af[4], bfr[4];
#pragma unroll
      for (int mi = 0; mi < 4; ++mi)
        af[mi] = *reinterpret_cast<const bf16x8*>(
            &ldsA[(wm * 64 + mi * 16 + l16) * 64 + (kk * 4 + lh) * 8]);
#pragma unroll
      for (int ni = 0; ni < 4; ++ni)
        bfr[ni] = *reinterpret_cast<const bf16x8*>(
            &ldsB[(wn * 64 + ni * 16 + l16) * 64 + (kk * 4 + lh) * 8]);
#pragma unroll
      for (int mi = 0; mi < 4; ++mi)
#pragma unroll
        for (int ni = 0; ni < 4; ++ni)
          acc[mi][ni] = __builtin_amdgcn_mfma_f32_16x16x32_bf16(af[mi], bfr[ni], acc[mi][ni], 0, 0, 0);
    }
  }

  // epilogue: D row = (lane>>4)*4 + r, col = lane&15 (m89-verified layout)
  const int rbase = wm * 64 + lh * 4;   // tile-local
  const int cbase = wn * 64 + l16;

  if constexpr (MODE == 0) {
    const int z = bn >> 3;               // 0=Q, 1=K, 2=V
    const int colbase = (bn & 7) * 128;
    if (z < 2) {
      u16* C = (u16*)Cg + (long)z * 8388608;
#pragma unroll
      for (int mi = 0; mi < 4; ++mi)
#pragma unroll
        for (int ni = 0; ni < 4; ++ni)
#pragma unroll
          for (int r = 0; r < 4; ++r)
            C[(long)(m0 + rbase + mi * 16 + r) * 1024 + colbase + cbase + ni * 16] =
                f2bf(acc[mi][ni][r]);
    } else {
      // V transposed: Vt[b][e][t], e in [0,1024), t in [0,2048)
      u16* C = (u16*)Cg + 16777216;      // Vt base (Qb + 2*8388608)
      const int b = m0 >> 11;
      const int t0 = (m0 & 2047) + rbase;
      const int e0 = colbase + cbase;
#pragma unroll
      for (int mi = 0; mi < 4; ++mi)
#pragma unroll
        for (int ni = 0; ni < 4; ++ni) {
          u16x4 o;
#pragma unroll
          for (int r = 0; r < 4; ++r) o[r] = f2bf(acc[mi][ni][r]);
          *reinterpret_cast<u16x4*>(
              &C[(long)b * 2097152 + (long)(e0 + ni * 16) * 2048 + t0 + mi * 16]) = o;
        }
    }
  } else if constexpr (MODE == 1) {
    u16* C = (u16*)Cg + (long)bz * sC;
#pragma unroll
    for (int mi = 0; mi < 4; ++mi)
#pragma unroll
      for (int ni = 0; ni < 4; ++ni)
#pragma unroll
        for (int r = 0; r < 4; ++r)
          C[(long)(m0 + rbase + mi * 16 + r) * 2048 + n0 + cbase + ni * 16] =
              f2bf(acc[mi][ni][r]);
  } else {
    float* C = (float*)Cg + (long)bz * sC;
#pragma unroll
    for (int mi = 0; mi < 4; ++mi)
#pragma unroll
      for (int ni = 0; ni < 4; ++ni)
#pragma unroll
        for (int r = 0; r < 4; ++r)
          C[(long)(m0 + rbase + mi * 16 + r) * 1024 + n0 + cbase + ni * 16] =
              acc[mi][ni][r];
  }
}

// ---------------- causal row softmax, in-place on bf16 S ----------------
// One block per row; thread tid owns elements [tid*8, tid*8+8) across all passes.
__global__ __launch_bounds__(256) void softmax_kernel(u16* __restrict__ S) {
  __shared__ float redm[4], reds[4];
  const int T = 2048;
  const long base = (long)blockIdx.x * T;
  const int q = blockIdx.x & (T - 1);
  const int len = q + 1;
  const int tid = threadIdx.x, lane = tid & 63, wid = tid >> 6;
  u16* row = S + base;
  const int k0 = tid * 8;

  float v[8];
  if (k0 < len) {
    u16x8 x = *reinterpret_cast<const u16x8*>(row + k0);
#pragma unroll
    for (int j = 0; j < 8; ++j) v[j] = bf2f(x[j]);
  }
  float m = -1e30f;
#pragma unroll
  for (int j = 0; j < 8; ++j)
    if (k0 + j < len) m = fmaxf(m, v[j]);
#pragma unroll
  for (int o = 32; o > 0; o >>= 1) m = fmaxf(m, __shfl_xor(m, o));
  if (lane == 0) redm[wid] = m;
  __syncthreads();
  const float mx = fmaxf(fmaxf(redm[0], redm[1]), fmaxf(redm[2], redm[3]));

  float e[8], s = 0.0f;
#pragma unroll
  for (int j = 0; j < 8; ++j) {
    e[j] = (k0 + j < len) ? __expf(v[j] - mx) : 0.0f;
    s += e[j];
  }
#pragma unroll
  for (int o = 32; o > 0; o >>= 1) s += __shfl_xor(s, o);
  if (lane == 0) reds[wid] = s;
  __syncthreads();
  const float inv = 1.0f / (reds[0] + reds[1] + reds[2] + reds[3]);

  u16x8 o;
#pragma unroll
  for (int j = 0; j < 8; ++j) o[j] = f2bf(e[j] * inv);
  *reinterpret_cast<u16x8*>(row + k0) = o;
}

extern "C" void kernel_launch(void* const* d_in, const int* in_sizes, int n_in,
                              void* d_out, int out_size, void* d_ws, size_t ws_size,
                              hipStream_t stream) {
  const float* X  = (const float*)d_in[0];
  const float* Wq = (const float*)d_in[1];
  const float* Wk = (const float*)d_in[2];
  const float* Wv = (const float*)d_in[3];

  // workspace layout (u16 elements)
  u16* Xb = (u16*)d_ws;                 // 8192*1024
  u16* Wt = Xb + 8388608;               // 3*1024*1024 ([3072][1024]; Wq rows pre-scaled 1/32)
  u16* Qb = Wt + 3145728;               // 8192*1024
  u16* Kb = Qb + 8388608;               // 8192*1024
  u16* Vt = Kb + 8388608;               // [b][1024][2048]
  u16* S  = Vt + 8388608;               // [b][2048][2048]
  // total = 107 MB

  cast_x_kernel<<<4096, 256, 0, stream>>>(X, Xb, 8388608L);
  transpose_cast_w<<<dim3(16, 16), 256, 0, stream>>>(Wq, Wt,           1.0f / 32.0f);
  transpose_cast_w<<<dim3(16, 16), 256, 0, stream>>>(Wk, Wt + 1048576, 1.0f);
  transpose_cast_w<<<dim3(16, 16), 256, 0, stream>>>(Wv, Wt + 2097152, 1.0f);

  // fused QKV projection (V written transposed)
  gemm_nt<0><<<1536, 256, 0, stream>>>(Xb, Wt, Qb, 1024, 0L, 0L, 0L);

  // S = Q K^T per batch (Q pre-scaled)
  gemm_nt<1><<<dim3(16, 16, 4), 256, 0, stream>>>(
      Qb, Kb, S, 1024, 2097152L, 2097152L, 4194304L);

  softmax_kernel<<<8192, 256, 0, stream>>>(S);

  // O = P V per batch
  gemm_nt<2><<<dim3(8, 16, 4), 256, 0, stream>>>(
      S, Vt, (float*)d_out, 2048, 4194304L, 2097152L, 2097152L);
}